// Round 5
// baseline (456.967 us; speedup 1.0000x reference)
//
#include <hip/hip_runtime.h>

#define BB 32
#define TT 243
#define JJ 17
#define CC 256
#define BJC (BB*JJ)          // 544
#define MM (BJC*TT)          // 132192 rows (bj-major: r = bj*TT + t)
#define SIMP 244             // padded sim row stride (16B-aligned rows)
#define NEG_INF (-3.0e38f)

typedef __attribute__((ext_vector_type(8))) short bf16x8;
typedef __attribute__((ext_vector_type(4))) float f32x4;
typedef __attribute__((ext_vector_type(8))) _Float16 f16x8;
typedef __attribute__((ext_vector_type(4))) _Float16 f16x4;

__device__ __forceinline__ unsigned short f2bf(float f) {
  unsigned int u = __float_as_uint(f);
  u = (u + 0x7fffu + ((u >> 16) & 1u)) >> 16;   // RNE
  return (unsigned short)u;
}
__device__ __forceinline__ float bf2f(unsigned short s) {
  return __uint_as_float(((unsigned int)s) << 16);
}

// ---------- K0b: W_u,W_v f32 [C,C] -> wc bf16 [512,C] ----------
__global__ void k_prep_w(const float* __restrict__ Wu, const float* __restrict__ Wv,
                         unsigned short* __restrict__ wc) {
  int g = blockIdx.x * 256 + threadIdx.x;
  if (g >= 512 * (CC/4)) return;
  int c4 = g & 63;
  int n  = g >> 6;
  const float* src = (n < CC) ? (Wu + (size_t)n*CC) : (Wv + (size_t)(n-CC)*CC);
  float4 v = *reinterpret_cast<const float4*>(src + c4*4);
  ushort4 o;
  o.x = f2bf(v.x); o.y = f2bf(v.y); o.z = f2bf(v.z); o.w = f2bf(v.w);
  *reinterpret_cast<ushort4*>(wc + (size_t)n*CC + c4*4) = o;
}

// ---------- K1: u,v = x @ [Wu;Wv]^T + b ----------
// One block = 128 rows x 512 cols. A staged ONCE in 64KB LDS (bf16, XOR-swizzled
// 16B units). B read direct global->reg (L2-resident weights). 2 passes (u, v),
// wave tile 64x128, 8 B-frags reuse each A-frag. No barriers in main loop.
__launch_bounds__(256, 2)
__global__ void k_uv(const float* __restrict__ x,
                     const unsigned short* __restrict__ wc,
                     const float* __restrict__ bu, const float* __restrict__ bv,
                     unsigned short* __restrict__ uo, unsigned short* __restrict__ vo) {
  __shared__ unsigned short Al[128 * 256];   // 64 KB exactly; unit-swizzled
  const int tid  = threadIdx.x;
  const int lane = tid & 63, wid = tid >> 6;
  const int wm = (wid >> 1) * 64;            // wave row offset
  const int wn = (wid & 1) * 128;            // wave col offset within 256-chunk
  const int m0 = blockIdx.x * 128;

  // ---- stage A: 128 rows x 256 k, f32 -> bf16, one pass ----
  {
    const int u = tid & 31;                  // 8-elem (16B) unit index 0..31
    const int r0 = tid >> 5;                 // 8 rows per iteration
    #pragma unroll
    for (int it = 0; it < 16; ++it) {
      int row = r0 + it * 8;
      int gm = m0 + row; if (gm > MM - 1) gm = MM - 1;
      int bj = gm / TT, t = gm - bj * TT;
      int b = bj / JJ, j = bj - b * JJ;
      const float* src = x + ((size_t)(b * TT + t) * JJ + j) * CC + u * 8;
      float4 v0 = *reinterpret_cast<const float4*>(src);
      float4 v1 = *reinterpret_cast<const float4*>(src + 4);
      ushort4 lo, hi;
      lo.x = f2bf(v0.x); lo.y = f2bf(v0.y); lo.z = f2bf(v0.z); lo.w = f2bf(v0.w);
      hi.x = f2bf(v1.x); hi.y = f2bf(v1.y); hi.z = f2bf(v1.z); hi.w = f2bf(v1.w);
      int su = u ^ (row & 7);                // bank swizzle
      *reinterpret_cast<ushort4*>(&Al[row * 256 + su * 8 + 0]) = lo;
      *reinterpret_cast<ushort4*>(&Al[row * 256 + su * 8 + 4]) = hi;
    }
  }
  __syncthreads();

  const int l15 = lane & 15;
  const int kfu = lane >> 4;                 // k-unit within 32-k step (0..3)
  const int rq4 = (lane >> 4) * 4;

  #pragma unroll
  for (int pass = 0; pass < 2; ++pass) {
    const float* bsrc = pass ? bv : bu;
    unsigned short* osrc = pass ? vo : uo;
    float bias[8];
    #pragma unroll
    for (int j = 0; j < 8; ++j) bias[j] = bsrc[wn + j * 16 + l15];

    f32x4 acc[4][8];
    #pragma unroll
    for (int i = 0; i < 4; i++)
      #pragma unroll
      for (int j = 0; j < 8; j++) acc[i][j] = (f32x4){0.f, 0.f, 0.f, 0.f};

    const unsigned short* wb = wc + ((size_t)pass * 256 + wn) * CC;
    #pragma unroll
    for (int ks = 0; ks < 8; ++ks) {
      bf16x8 af[4], bfv[8];
      #pragma unroll
      for (int j = 0; j < 8; ++j)
        bfv[j] = *reinterpret_cast<const bf16x8*>(wb + (size_t)(j * 16 + l15) * CC + ks * 32 + kfu * 8);
      #pragma unroll
      for (int i = 0; i < 4; ++i) {
        int row = wm + i * 16 + l15;
        int su = (ks * 4 + kfu) ^ (row & 7);
        af[i] = *reinterpret_cast<const bf16x8*>(&Al[row * 256 + su * 8]);
      }
      #pragma unroll
      for (int i = 0; i < 4; ++i)
        #pragma unroll
        for (int j = 0; j < 8; ++j)
          acc[i][j] = __builtin_amdgcn_mfma_f32_16x16x32_bf16(af[i], bfv[j], acc[i][j], 0, 0, 0);
    }

    #pragma unroll
    for (int i = 0; i < 4; ++i) {
      #pragma unroll
      for (int q = 0; q < 4; ++q) {
        int gm = m0 + wm + i * 16 + rq4 + q;
        if (gm < MM) {
          #pragma unroll
          for (int j = 0; j < 8; ++j)
            osrc[(size_t)gm * CC + wn + j * 16 + l15] = f2bf(acc[i][j][q] + bias[j]);
        }
      }
    }
  }
}

// ---------- K2: sim = xr @ xr^T per bj via split-fp16 MFMA (3 passes) ----------
__launch_bounds__(256)
__global__ void k_sim(const float* __restrict__ x, float* __restrict__ sim) {
  __shared__ _Float16 Ah[128][40];   // +8 pad halves (16B)
  __shared__ _Float16 Al[128][40];
  __shared__ _Float16 Bh[128][40];
  __shared__ _Float16 Bl[128][40];
  const int tile = blockIdx.x;                 // 0..3: mt = tile>>1, nt = tile&1
  const int bj = blockIdx.y;
  const int m0 = (tile >> 1) * 128, n0 = (tile & 1) * 128;
  const int b = bj / JJ, jj = bj - b * JJ;
  const float* xb = x + ((size_t)b * TT * JJ + jj) * CC;   // + t*(JJ*CC) + k
  const int tid = threadIdx.x;
  const int lane = tid & 63, wid = tid >> 6;
  const int wm = (wid >> 1) * 64, wn = (wid & 1) * 64;

  const int kq = tid & 7;
  int ra[4], rb[4];
  const float *gpa[4], *gpb[4];
  #pragma unroll
  for (int it = 0; it < 4; ++it) {
    int r = (tid >> 3) + it * 32;
    ra[it] = r; rb[it] = r;
    int ta = m0 + r; if (ta > TT - 1) ta = TT - 1;
    int tb = n0 + r; if (tb > TT - 1) tb = TT - 1;
    gpa[it] = xb + (size_t)ta * (JJ * CC);
    gpb[it] = xb + (size_t)tb * (JJ * CC);
  }

  f32x4 acc[4][4];
  #pragma unroll
  for (int i = 0; i < 4; i++)
    #pragma unroll
    for (int j = 0; j < 4; j++) acc[i][j] = (f32x4){0.f, 0.f, 0.f, 0.f};

  for (int ks = 0; ks < CC; ks += 32) {
    #pragma unroll
    for (int it = 0; it < 4; ++it) {
      float4 va = *reinterpret_cast<const float4*>(gpa[it] + ks + kq * 4);
      _Float16 h0 = (_Float16)va.x, h1 = (_Float16)va.y,
               h2 = (_Float16)va.z, h3 = (_Float16)va.w;
      f16x4 hv = (f16x4){h0, h1, h2, h3};
      f16x4 lv = (f16x4){(_Float16)(va.x - (float)h0), (_Float16)(va.y - (float)h1),
                         (_Float16)(va.z - (float)h2), (_Float16)(va.w - (float)h3)};
      *reinterpret_cast<f16x4*>(&Ah[ra[it]][kq * 4]) = hv;
      *reinterpret_cast<f16x4*>(&Al[ra[it]][kq * 4]) = lv;
      float4 vb = *reinterpret_cast<const float4*>(gpb[it] + ks + kq * 4);
      h0 = (_Float16)vb.x; h1 = (_Float16)vb.y; h2 = (_Float16)vb.z; h3 = (_Float16)vb.w;
      hv = (f16x4){h0, h1, h2, h3};
      lv = (f16x4){(_Float16)(vb.x - (float)h0), (_Float16)(vb.y - (float)h1),
                   (_Float16)(vb.z - (float)h2), (_Float16)(vb.w - (float)h3)};
      *reinterpret_cast<f16x4*>(&Bh[rb[it]][kq * 4]) = hv;
      *reinterpret_cast<f16x4*>(&Bl[rb[it]][kq * 4]) = lv;
    }
    __syncthreads();
    const int kf = (lane >> 4) * 8;
    f16x8 ah[4], al[4], bh[4], bl[4];
    #pragma unroll
    for (int i = 0; i < 4; i++) {
      ah[i] = *reinterpret_cast<const f16x8*>(&Ah[wm + i * 16 + (lane & 15)][kf]);
      al[i] = *reinterpret_cast<const f16x8*>(&Al[wm + i * 16 + (lane & 15)][kf]);
    }
    #pragma unroll
    for (int j = 0; j < 4; j++) {
      bh[j] = *reinterpret_cast<const f16x8*>(&Bh[wn + j * 16 + (lane & 15)][kf]);
      bl[j] = *reinterpret_cast<const f16x8*>(&Bl[wn + j * 16 + (lane & 15)][kf]);
    }
    #pragma unroll
    for (int i = 0; i < 4; i++)
      #pragma unroll
      for (int j = 0; j < 4; j++) {
        acc[i][j] = __builtin_amdgcn_mfma_f32_16x16x32_f16(ah[i], bh[j], acc[i][j], 0, 0, 0);
        acc[i][j] = __builtin_amdgcn_mfma_f32_16x16x32_f16(ah[i], bl[j], acc[i][j], 0, 0, 0);
        acc[i][j] = __builtin_amdgcn_mfma_f32_16x16x32_f16(al[i], bh[j], acc[i][j], 0, 0, 0);
      }
    __syncthreads();
  }

  const size_t base = (size_t)bj * TT * SIMP;
  const int rq = (lane >> 4) * 4;                  // C/D: col=lane&15, row=(lane>>4)*4+q
  #pragma unroll
  for (int i = 0; i < 4; i++) {
    #pragma unroll
    for (int q = 0; q < 4; q++) {
      int n = m0 + wm + i * 16 + rq + q;
      if (n < TT) {
        #pragma unroll
        for (int j = 0; j < 4; j++) {
          int c = n0 + wn + j * 16 + (lane & 15);
          if (c < TT) sim[base + (size_t)n * SIMP + c] = acc[i][j][q];
        }
      }
    }
  }
}

// ---------- K3a: per row: thr, dis, adjacency bitmask (4 waves = 4 rows/block) ----------
__launch_bounds__(256)
__global__ void k_topk(const float* __restrict__ sim,
                       float* __restrict__ dis_o,
                       unsigned long long* __restrict__ mask_o) {
  const int l = threadIdx.x & 63, wv = threadIdx.x >> 6;
  const int r = blockIdx.x * 4 + wv;               // MM % 4 == 0
  const float* row = sim + (size_t)r * SIMP;
  float o0 = (l       < TT) ? row[l]       : NEG_INF;
  float o1 = (l + 64  < TT) ? row[l + 64]  : NEG_INF;
  float o2 = (l + 128 < TT) ? row[l + 128] : NEG_INF;
  float o3 = (l + 192 < TT) ? row[l + 192] : NEG_INF;
  float v0 = o0, v1 = o1, v2 = o2, v3 = o3;
  { float mx, mn;
    mx=fmaxf(v0,v1); mn=fminf(v0,v1); v0=mx; v1=mn;
    mx=fmaxf(v2,v3); mn=fminf(v2,v3); v2=mx; v3=mn;
    mx=fmaxf(v0,v2); mn=fminf(v0,v2); v0=mx; v2=mn;
    mx=fmaxf(v1,v3); mn=fminf(v1,v3); v1=mx; v3=mn;
    mx=fmaxf(v1,v2); mn=fminf(v1,v2); v1=mx; v2=mn; }
  int p = 0;
  float thr = NEG_INF;
  #pragma unroll
  for (int it = 0; it < 4; ++it) {
    float head = (p == 0) ? v0 : (p == 1) ? v1 : (p == 2) ? v2 : (p == 3) ? v3 : NEG_INF;
    float m = head;
    #pragma unroll
    for (int off = 1; off < 64; off <<= 1) m = fmaxf(m, __shfl_xor(m, off));
    thr = m;
    unsigned long long msk = __ballot(head == m);
    int first = __ffsll(msk) - 1;
    if (l == first) p++;
  }
  unsigned long long m0 = __ballot(o0 >= thr);
  unsigned long long m1 = __ballot(o1 >= thr);
  unsigned long long m2 = __ballot(o2 >= thr);
  unsigned long long m3 = __ballot(o3 >= thr);
  if (l == 0) {
    int deg = __popcll(m0) + __popcll(m1) + __popcll(m2) + __popcll(m3);
    dis_o[r] = rsqrtf((float)deg);
    mask_o[(size_t)r * 4 + 0] = m0;
    mask_o[(size_t)r * 4 + 1] = m1;
    mask_o[(size_t)r * 4 + 2] = m2;
    mask_o[(size_t)r * 4 + 3] = m3;
  }
}

// ---------- K3b: h = norm_adj @ v + u (one wave per row, 4 ch/lane) ----------
__launch_bounds__(512)
__global__ void k_agg(const unsigned long long* __restrict__ mask,
                      const float* __restrict__ dis, const unsigned short* __restrict__ u,
                      const unsigned short* __restrict__ v, unsigned short* __restrict__ h,
                      float* __restrict__ p1, float* __restrict__ p2) {
  __shared__ float dis_l[256];
  const int bj = blockIdx.x;
  const int tid = threadIdx.x, lane = tid & 63, wid = tid >> 6;
  if (tid < TT) dis_l[tid] = dis[(size_t)bj * TT + tid];
  __syncthreads();
  const int start = blockIdx.y * 122;
  const int cnt = blockIdx.y ? (TT - 122) : 122;
  const size_t pbase = (size_t)bj * TT;
  for (int rl = wid; rl < cnt; rl += 8) {
    const int t = start + rl;
    const size_t r = pbase + t;
    const float dr = dis_l[t];
    ushort4 uu = *reinterpret_cast<const ushort4*>(u + r * CC + lane * 4);
    float a0 = bf2f(uu.x), a1 = bf2f(uu.y), a2 = bf2f(uu.z), a3 = bf2f(uu.w);
    #pragma unroll
    for (int w4 = 0; w4 < 4; ++w4) {
      unsigned long long m = mask[r * 4 + w4];
      while (m) {
        int i = __ffsll(m) - 1;
        m &= m - 1;
        int idx = w4 * 64 + i;
        float w = dr * dis_l[idx];
        ushort4 vv = *reinterpret_cast<const ushort4*>(v + (pbase + idx) * CC + lane * 4);
        a0 = __builtin_fmaf(w, bf2f(vv.x), a0);
        a1 = __builtin_fmaf(w, bf2f(vv.y), a1);
        a2 = __builtin_fmaf(w, bf2f(vv.z), a2);
        a3 = __builtin_fmaf(w, bf2f(vv.w), a3);
      }
    }
    ushort4 hh;
    hh.x = f2bf(a0); hh.y = f2bf(a1); hh.z = f2bf(a2); hh.w = f2bf(a3);
    *reinterpret_cast<ushort4*>(h + r * CC + lane * 4) = hh;
    float s1 = a0 + a1 + a2 + a3;
    float s2 = a0*a0 + a1*a1 + a2*a2 + a3*a3;
    #pragma unroll
    for (int off = 1; off < 64; off <<= 1) { s1 += __shfl_xor(s1, off); s2 += __shfl_xor(s2, off); }
    if (lane == 0) { p1[r] = s1; p2[r] = s2; }
  }
}

// ---------- K4: BN stats per t -> scale/shift ----------
__global__ void k_bnstat(const float* __restrict__ p1, const float* __restrict__ p2,
                         const float* __restrict__ gamma, const float* __restrict__ beta,
                         float* __restrict__ scale, float* __restrict__ shift) {
  __shared__ float sA[256], sB[256];
  const int t = blockIdx.x;
  const int tid = threadIdx.x;
  float a = 0.f, b2 = 0.f;
  for (int bj = tid; bj < BJC; bj += 256) {
    a  += p1[bj * TT + t];
    b2 += p2[bj * TT + t];
  }
  sA[tid] = a; sB[tid] = b2;
  __syncthreads();
  for (int s = 128; s > 0; s >>= 1) {
    if (tid < s) { sA[tid] += sA[tid + s]; sB[tid] += sB[tid + s]; }
    __syncthreads();
  }
  if (tid == 0) {
    const float invN = 1.0f / (float)(BJC * CC);
    float mean = sA[0] * invN;
    float var  = sB[0] * invN - mean * mean;
    float sc   = rsqrtf(var + 1e-5f) * gamma[t];
    scale[t] = sc;
    shift[t] = beta[t] - mean * sc;
  }
}

// ---------- K5: out = relu(x + h*scale + shift), back to [B,T,J,C] ----------
__global__ void k_out(const float* __restrict__ x, const unsigned short* __restrict__ h,
                      const float* __restrict__ scale, const float* __restrict__ shift,
                      float* __restrict__ out) {
  int g = blockIdx.x * 256 + threadIdx.x;
  if (g >= MM * (CC/4)) return;
  int c4  = g & 63;
  int rowx = g >> 6;
  int b   = rowx / (TT*JJ);
  int rem = rowx - b*(TT*JJ);
  int t   = rem / JJ;
  int j   = rem - t*JJ;
  size_t hoff = ((size_t)(b*JJ + j) * TT + t) * CC + c4*4;
  float4 xv = *reinterpret_cast<const float4*>(x + (size_t)rowx*CC + c4*4);
  ushort4 hv = *reinterpret_cast<const ushort4*>(h + hoff);
  float sc = scale[t], sh = shift[t];
  float4 o;
  o.x = fmaxf(xv.x + bf2f(hv.x)*sc + sh, 0.f);
  o.y = fmaxf(xv.y + bf2f(hv.y)*sc + sh, 0.f);
  o.z = fmaxf(xv.z + bf2f(hv.z)*sc + sh, 0.f);
  o.w = fmaxf(xv.w + bf2f(hv.w)*sc + sh, 0.f);
  *reinterpret_cast<float4*>(out + (size_t)rowx*CC + c4*4) = o;
}

extern "C" void kernel_launch(void* const* d_in, const int* in_sizes, int n_in,
                              void* d_out, int out_size, void* d_ws, size_t ws_size,
                              hipStream_t stream) {
  const float* x     = (const float*)d_in[0];
  const float* Wu    = (const float*)d_in[1];
  const float* bu    = (const float*)d_in[2];
  const float* Wv    = (const float*)d_in[3];
  const float* bv    = (const float*)d_in[4];
  const float* gamma = (const float*)d_in[5];
  const float* beta  = (const float*)d_in[6];
  float* out = (float*)d_out;

  char* ws = (char*)d_ws;
  size_t off = 0;
  auto alloc = [&](size_t bytes) -> void* {
    void* p = ws + off;
    off = (off + bytes + 255) & ~(size_t)255;
    return p;
  };
  unsigned short* u   = (unsigned short*)alloc((size_t)MM * CC * 2);
  unsigned short* v   = (unsigned short*)alloc((size_t)MM * CC * 2);
  unsigned short* h   = (unsigned short*)alloc((size_t)MM * CC * 2);
  unsigned short* wc  = (unsigned short*)alloc((size_t)512 * CC * 2);
  float* sim = (float*)alloc((size_t)BJC * TT * SIMP * 4);
  float* dis = (float*)alloc((size_t)MM * 4);
  unsigned long long* msk = (unsigned long long*)alloc((size_t)MM * 4 * 8);
  float* p1    = (float*)alloc((size_t)MM * 4);
  float* p2    = (float*)alloc((size_t)MM * 4);
  float* scale = (float*)alloc(1024);
  float* shift = (float*)alloc(1024);

  if (ws_size < off) {
    hipMemsetAsync(d_out, 0, (size_t)out_size * 4, stream);
    return;
  }

  k_prep_w<<<dim3((512*(CC/4) + 255)/256), dim3(256), 0, stream>>>(Wu, Wv, wc);
  k_sim  <<<dim3(4, BJC), dim3(256), 0, stream>>>(x, sim);
  k_uv   <<<dim3((MM + 127)/128), dim3(256), 0, stream>>>(x, wc, bu, bv, u, v);
  k_topk <<<dim3(MM/4), dim3(256), 0, stream>>>(sim, dis, msk);
  k_agg  <<<dim3(BJC, 2), dim3(512), 0, stream>>>(msk, dis, u, v, h, p1, p2);
  k_bnstat<<<dim3(TT), dim3(256), 0, stream>>>(p1, p2, gamma, beta, scale, shift);
  k_out  <<<dim3((MM*(CC/4) + 255)/256), dim3(256), 0, stream>>>(x, h, scale, shift, out);
}